// Round 6
// baseline (22256.882 us; speedup 1.0000x reference)
//
#include <hip/hip_runtime.h>
#include <cstdint>
#include <cstddef>

#define HH 512
#define DD 256
#define BB 64
#define SS 2048
#define G3 1536

typedef float f32x4 __attribute__((ext_vector_type(4)));

// LDS layout for gru_scan (floats): Wl[48][516] | hl[8][516] | xil[8][52] | hhl[8][49]
#define SMEM_FLOATS (48*516 + 8*516 + 8*52 + 8*49)
#define SMEM_BYTES  (SMEM_FLOATS * 4)

// ---------------- Wh [512][1536] -> Wt [1536][512] ----------------
__global__ __launch_bounds__(256) void transpose_wh(const float* __restrict__ Wh,
                                                    float* __restrict__ Wt) {
    __shared__ float t[32][33];
    int bx = blockIdx.x % 48;            // g tile
    int by = blockIdx.x / 48;            // k tile
    int x = threadIdx.x & 31, y0 = threadIdx.x >> 5;
#pragma unroll
    for (int i = 0; i < 32; i += 8)
        t[y0 + i][x] = Wh[(size_t)(by * 32 + y0 + i) * G3 + bx * 32 + x];
    __syncthreads();
#pragma unroll
    for (int i = 0; i < 32; i += 8)
        Wt[(size_t)(bx * 32 + y0 + i) * HH + by * 32 + x] = t[x][y0 + i];
}

// ------------- fused embedding gather + xi GEMM: xi[m][g] = emb[tok(m)] @ Wi + bi -------------
__global__ __launch_bounds__(256, 2) void xi_gemm(const int* __restrict__ tokens,
                                                  const float* __restrict__ emb,
                                                  const float* __restrict__ Wi,
                                                  const float* __restrict__ bi,
                                                  float* __restrict__ xi,
                                                  int chunk_start, int SC) {
    __shared__ float Al[8][132];
    __shared__ float Bl[8][132];
    __shared__ int   toks[128];
    const int tid = threadIdx.x;
    const int m0 = blockIdx.x * 128;
    const int n0 = blockIdx.y * 128;
    if (tid < 128) {
        int m = m0 + tid;
        int b = m / SC, s = m % SC;
        toks[tid] = tokens[b * SS + chunk_start + s];
    }
    float acc[8][8];
#pragma unroll
    for (int i = 0; i < 8; ++i)
#pragma unroll
        for (int j = 0; j < 8; ++j) acc[i][j] = 0.f;
    const int tm = tid & 15, tn = (tid >> 4) & 15;
    const int ma = tid & 127, kq = tid >> 7;
    const int bk = tid >> 5,  bn = tid & 31;
    __syncthreads();
    for (int k0 = 0; k0 < DD; k0 += 8) {
        float4 av = *(const float4*)(emb + (size_t)toks[ma] * DD + k0 + kq * 4);
        float4 bv = *(const float4*)(Wi + (size_t)(k0 + bk) * G3 + n0 + bn * 4);
        Al[kq*4+0][ma] = av.x; Al[kq*4+1][ma] = av.y;
        Al[kq*4+2][ma] = av.z; Al[kq*4+3][ma] = av.w;
        *(float4*)&Bl[bk][bn*4] = bv;
        __syncthreads();
#pragma unroll
        for (int k = 0; k < 8; ++k) {
            float a[8], bbv[8];
            *(float4*)&a[0]   = *(const float4*)&Al[k][tm*4];
            *(float4*)&a[4]   = *(const float4*)&Al[k][64 + tm*4];
            *(float4*)&bbv[0] = *(const float4*)&Bl[k][tn*4];
            *(float4*)&bbv[4] = *(const float4*)&Bl[k][64 + tn*4];
#pragma unroll
            for (int i = 0; i < 8; ++i)
#pragma unroll
                for (int j = 0; j < 8; ++j) acc[i][j] += a[i] * bbv[j];
        }
        __syncthreads();
    }
    float4 b0v = *(const float4*)(bi + n0 + tn*4);
    float4 b1v = *(const float4*)(bi + n0 + 64 + tn*4);
#pragma unroll
    for (int i = 0; i < 8; ++i) {
        int m = m0 + (i < 4 ? tm*4 + i : 64 + tm*4 + (i - 4));
        float* orow = xi + (size_t)m * G3 + n0;
        float4 o0 = make_float4(acc[i][0]+b0v.x, acc[i][1]+b0v.y, acc[i][2]+b0v.z, acc[i][3]+b0v.w);
        float4 o1 = make_float4(acc[i][4]+b1v.x, acc[i][5]+b1v.y, acc[i][6]+b1v.z, acc[i][7]+b1v.w);
        *(float4*)(orow + tn*4) = o0;
        *(float4*)(orow + 64 + tn*4) = o1;
    }
}

// ------------- GRU scan: 8 batch-groups x 32 j-slice wgs (grid 256) -------------
// R2 base + ONLY (b): shfl_xor k-reduce replacing the prt LDS round-trip.
// Weights stay in LDS (Wl) exactly as the passing R2.
__global__ __launch_bounds__(256, 1) void gru_scan(const float* __restrict__ xi,
                                                   const float* __restrict__ Wt,
                                                   const float* __restrict__ bhn,
                                                   float* __restrict__ hbuf,
                                                   unsigned int* __restrict__ cnt,
                                                   float* __restrict__ out,
                                                   int chunk_start, int SC) {
    extern __shared__ float smf[];
    float* Wl  = smf;                    // [48][516]
    float* hl  = Wl  + 48*516;           // [8][516]
    float* xil = hl  + 8*516;            // [8][52]
    float* hhl = xil + 8*52;             // [8][49]

    const int tid = threadIdx.x;
    const int grp = blockIdx.x & 7;      // batch group
    const int mem = blockIdx.x >> 3;     // j-slice 0..31
    const int j0 = mem * 16;
    const int b0 = grp * 8;

    // Load Wh slice: 48 gate-cols (c = gate*16+jj) x 512 k, coalesced from Wt[g][k].
    for (int i = tid; i < 48 * 128; i += 256) {
        int c = i >> 7, kq2 = (i & 127) << 2;
        int g = (c >> 4) * HH + j0 + (c & 15);
        *(float4*)&Wl[c * 516 + kq2] = *(const float4*)(Wt + (size_t)g * HH + kq2);
    }
    float bhn_r = 0.f;
    if (tid < 128) bhn_r = bhn[j0 + (tid & 15)];

    const int tg = tid >> 4, ks = tid & 15;   // 16 col-groups x 16 k-slices
    unsigned int* cptr = &cnt[grp << 6];
    unsigned int target = 0;
    const int bh = tid >> 7;             // 0/1
    const int kq = (tid & 127) << 2;

    for (int s = 0; s < SC; ++s) {
        const int t = chunk_start + s;
        const float* hsrc = hbuf + (size_t)(t & 1) * (BB * HH);
        float*       hdst = hbuf + (size_t)((t + 1) & 1) * (BB * HH);

        // stage h(t) for our 8 batches: 4 x dwordx4 sc0 sc1 per thread (L3-coherent)
        {
            const float* p0 = hsrc + (size_t)(b0 + bh) * HH + kq;
            const float* p1 = p0 + 2 * HH;
            const float* p2 = p0 + 4 * HH;
            const float* p3 = p0 + 6 * HH;
            f32x4 h0v, h1v, h2v, h3v;
            asm volatile(
                "global_load_dwordx4 %0, %4, off sc0 sc1\n\t"
                "global_load_dwordx4 %1, %5, off sc0 sc1\n\t"
                "global_load_dwordx4 %2, %6, off sc0 sc1\n\t"
                "global_load_dwordx4 %3, %7, off sc0 sc1\n\t"
                "s_waitcnt vmcnt(0)"
                : "=&v"(h0v), "=&v"(h1v), "=&v"(h2v), "=&v"(h3v)
                : "v"(p0), "v"(p1), "v"(p2), "v"(p3)
                : "memory");
            *(f32x4*)&hl[(bh + 0) * 516 + kq] = h0v;
            *(f32x4*)&hl[(bh + 2) * 516 + kq] = h1v;
            *(f32x4*)&hl[(bh + 4) * 516 + kq] = h2v;
            *(f32x4*)&hl[(bh + 6) * 516 + kq] = h3v;
        }
        // stage xi(t) for (8 b x 3 gates x 16 j): 96 float4 (normal cached loads)
        if (tid < 96) {
            int b = tid / 12, q = tid % 12;
            int gate = q >> 2, f = (q & 3) << 2;
            *(float4*)&xil[b * 52 + gate * 16 + f] =
                *(const float4*)(xi + ((size_t)(b0 + b) * SC + s) * G3 + gate * HH + j0 + f);
        }
        __syncthreads();
        // MAC: thread = (tg, ks): 8 batches x 3 g-cols x 32 k, weights from LDS (as R2)
        float acc[3][8];
#pragma unroll
        for (int gi = 0; gi < 3; ++gi)
#pragma unroll
            for (int b = 0; b < 8; ++b) acc[gi][b] = 0.f;
#pragma unroll
        for (int m = 0; m < 8; ++m) {
            int k = (ks << 2) + (m << 6);
            float4 w0 = *(const float4*)&Wl[(3*tg+0)*516 + k];
            float4 w1 = *(const float4*)&Wl[(3*tg+1)*516 + k];
            float4 w2 = *(const float4*)&Wl[(3*tg+2)*516 + k];
#pragma unroll
            for (int b = 0; b < 8; ++b) {
                float4 hv = *(const float4*)&hl[b*516 + k];
                acc[0][b] += w0.x*hv.x + w0.y*hv.y + w0.z*hv.z + w0.w*hv.w;
                acc[1][b] += w1.x*hv.x + w1.y*hv.y + w1.z*hv.z + w1.w*hv.w;
                acc[2][b] += w2.x*hv.x + w2.y*hv.y + w2.z*hv.z + w2.w*hv.w;
            }
        }
        // (b) reduce over the 16 ks lanes (aligned 16-lane segments) via shfl_xor
#pragma unroll
        for (int gi = 0; gi < 3; ++gi)
#pragma unroll
            for (int b = 0; b < 8; ++b) {
                float v = acc[gi][b];
                v += __shfl_xor(v, 1, 16);
                v += __shfl_xor(v, 2, 16);
                v += __shfl_xor(v, 4, 16);
                v += __shfl_xor(v, 8, 16);
                if (ks == (((gi << 3) | b) & 15)) hhl[b * 49 + 3 * tg + gi] = v;
            }
        __syncthreads();   // hhl ready
        // gates + state update for (8 b x 16 j)
        if (tid < 128) {
            int b = tid >> 4, jj = tid & 15;
            float hhR = hhl[b*49 + jj];
            float hhZ = hhl[b*49 + 16 + jj];
            float hhN = hhl[b*49 + 32 + jj];
            float xiR = xil[b*52 + jj];
            float xiZ = xil[b*52 + 16 + jj];
            float xiN = xil[b*52 + 32 + jj];
            float hold = hl[b*516 + j0 + jj];
            float r = 1.f / (1.f + expf(-(xiR + hhR)));
            float z = 1.f / (1.f + expf(-(xiZ + hhZ)));
            float n = tanhf(xiN + r * (hhN + bhn_r));
            float hnew = (1.f - z) * n + z * hold;
            float* hp = hdst + (size_t)(b0 + b) * HH + j0 + jj;
            asm volatile("global_store_dword %0, %1, off sc0 sc1"
                         :: "v"(hp), "v"(hnew) : "memory");
            out[((size_t)(b0 + b) * SS + t) * HH + j0 + jj] = hnew;
        }
        // release: sc1 store retirement == visible at coherence point
        asm volatile("s_waitcnt vmcnt(0)" ::: "memory");
        __syncthreads();
        target += 32;
        if (tid == 0) {
            __hip_atomic_fetch_add(cptr, 1u, __ATOMIC_RELAXED, __HIP_MEMORY_SCOPE_AGENT);
            unsigned int v;
            do {
                asm volatile(
                    "global_load_dword %0, %1, off sc0 sc1\n\t"
                    "s_waitcnt vmcnt(0)"
                    : "=v"(v) : "v"(cptr) : "memory");
                if (v >= target) break;
                asm volatile("s_sleep 1");
            } while (true);
        }
        __syncthreads();
    }
}

extern "C" void kernel_launch(void* const* d_in, const int* in_sizes, int n_in,
                              void* d_out, int out_size, void* d_ws, size_t ws_size,
                              hipStream_t stream) {
    const int*   tokens = (const int*)d_in[0];
    const float* emb    = (const float*)d_in[1];
    const float* Wi     = (const float*)d_in[2];
    const float* bi     = (const float*)d_in[3];
    const float* Wh     = (const float*)d_in[4];
    const float* bhn    = (const float*)d_in[5];
    float* out = (float*)d_out;

    char* ws = (char*)d_ws;
    float*        Wt   = (float*)ws;                                  // 3 MB
    float*        hbuf = (float*)(ws + (3 << 20));                    // 2 x 128 KB ping-pong
    unsigned int* cnt  = (unsigned int*)(ws + (3 << 20) + BB*HH*2*4); // 8 x 256B counters
    float*        xi   = (float*)(ws + (4 << 20));                    // chunk xi buffer

    size_t avail = ws_size > ((size_t)4 << 20) ? ws_size - ((size_t)4 << 20) : 0;
    int SC = 64;
    const int cands[5] = {2048, 1024, 512, 256, 128};
    for (int i = 0; i < 5; ++i) {
        if ((size_t)cands[i] * BB * G3 * 4 <= avail) { SC = cands[i]; break; }
    }

    hipFuncSetAttribute((const void*)gru_scan,
                        hipFuncAttributeMaxDynamicSharedMemorySize, SMEM_BYTES);

    hipMemsetAsync(hbuf, 0, BB * HH * 2 * 4, stream);
    transpose_wh<<<768, 256, 0, stream>>>(Wh, Wt);

    int nch = SS / SC;
    for (int c = 0; c < nch; ++c) {
        int cs = c * SC;
        xi_gemm<<<dim3((BB * SC) / 128, 12), 256, 0, stream>>>(tokens, emb, Wi, bi, xi, cs, SC);
        hipMemsetAsync(cnt, 0, 8 * 64 * 4, stream);
        void* args[] = {(void*)&xi, (void*)&Wt, (void*)&bhn, (void*)&hbuf,
                        (void*)&cnt, (void*)&out, (void*)&cs, (void*)&SC};
        hipError_t ce = hipLaunchCooperativeKernel((void*)gru_scan, dim3(256), dim3(256),
                                                   args, SMEM_BYTES, stream);
        if (ce != hipSuccess) {
            // Fallback: plain launch. Grid = 256 blocks at 1 block/CU occupancy on 256 CUs
            // -> fully co-resident, so the counter barrier cannot deadlock.
            gru_scan<<<dim3(256), dim3(256), SMEM_BYTES, stream>>>(
                xi, Wt, bhn, hbuf, cnt, out, cs, SC);
        }
    }
}

// Round 7
// 17004.105 us; speedup vs baseline: 1.3089x; 1.3089x over previous
//
#include <hip/hip_runtime.h>
#include <cstdint>
#include <cstddef>

#define HH 512
#define DD 256
#define BB 64
#define SS 2048
#define G3 1536

typedef float f32x4 __attribute__((ext_vector_type(4)));

// LDS layout for gru_scan (floats): Wl[48][516] | hl[8][516] | xil[8][52] | hhl[8][49]
#define SMEM_FLOATS (48*516 + 8*516 + 8*52 + 8*49)
#define SMEM_BYTES  (SMEM_FLOATS * 4)

// ---------------- Wh [512][1536] -> Wt [1536][512] ----------------
__global__ __launch_bounds__(256) void transpose_wh(const float* __restrict__ Wh,
                                                    float* __restrict__ Wt) {
    __shared__ float t[32][33];
    int bx = blockIdx.x % 48;            // g tile
    int by = blockIdx.x / 48;            // k tile
    int x = threadIdx.x & 31, y0 = threadIdx.x >> 5;
#pragma unroll
    for (int i = 0; i < 32; i += 8)
        t[y0 + i][x] = Wh[(size_t)(by * 32 + y0 + i) * G3 + bx * 32 + x];
    __syncthreads();
#pragma unroll
    for (int i = 0; i < 32; i += 8)
        Wt[(size_t)(bx * 32 + y0 + i) * HH + by * 32 + x] = t[x][y0 + i];
}

// ------------- fused embedding gather + xi GEMM: xi[m][g] = emb[tok(m)] @ Wi + bi -------------
__global__ __launch_bounds__(256, 2) void xi_gemm(const int* __restrict__ tokens,
                                                  const float* __restrict__ emb,
                                                  const float* __restrict__ Wi,
                                                  const float* __restrict__ bi,
                                                  float* __restrict__ xi,
                                                  int chunk_start, int SC) {
    __shared__ float Al[8][132];
    __shared__ float Bl[8][132];
    __shared__ int   toks[128];
    const int tid = threadIdx.x;
    const int m0 = blockIdx.x * 128;
    const int n0 = blockIdx.y * 128;
    if (tid < 128) {
        int m = m0 + tid;
        int b = m / SC, s = m % SC;
        toks[tid] = tokens[b * SS + chunk_start + s];
    }
    float acc[8][8];
#pragma unroll
    for (int i = 0; i < 8; ++i)
#pragma unroll
        for (int j = 0; j < 8; ++j) acc[i][j] = 0.f;
    const int tm = tid & 15, tn = (tid >> 4) & 15;
    const int ma = tid & 127, kq = tid >> 7;
    const int bk = tid >> 5,  bn = tid & 31;
    __syncthreads();
    for (int k0 = 0; k0 < DD; k0 += 8) {
        float4 av = *(const float4*)(emb + (size_t)toks[ma] * DD + k0 + kq * 4);
        float4 bv = *(const float4*)(Wi + (size_t)(k0 + bk) * G3 + n0 + bn * 4);
        Al[kq*4+0][ma] = av.x; Al[kq*4+1][ma] = av.y;
        Al[kq*4+2][ma] = av.z; Al[kq*4+3][ma] = av.w;
        *(float4*)&Bl[bk][bn*4] = bv;
        __syncthreads();
#pragma unroll
        for (int k = 0; k < 8; ++k) {
            float a[8], bbv[8];
            *(float4*)&a[0]   = *(const float4*)&Al[k][tm*4];
            *(float4*)&a[4]   = *(const float4*)&Al[k][64 + tm*4];
            *(float4*)&bbv[0] = *(const float4*)&Bl[k][tn*4];
            *(float4*)&bbv[4] = *(const float4*)&Bl[k][64 + tn*4];
#pragma unroll
            for (int i = 0; i < 8; ++i)
#pragma unroll
                for (int j = 0; j < 8; ++j) acc[i][j] += a[i] * bbv[j];
        }
        __syncthreads();
    }
    float4 b0v = *(const float4*)(bi + n0 + tn*4);
    float4 b1v = *(const float4*)(bi + n0 + 64 + tn*4);
#pragma unroll
    for (int i = 0; i < 8; ++i) {
        int m = m0 + (i < 4 ? tm*4 + i : 64 + tm*4 + (i - 4));
        float* orow = xi + (size_t)m * G3 + n0;
        float4 o0 = make_float4(acc[i][0]+b0v.x, acc[i][1]+b0v.y, acc[i][2]+b0v.z, acc[i][3]+b0v.w);
        float4 o1 = make_float4(acc[i][4]+b1v.x, acc[i][5]+b1v.y, acc[i][6]+b1v.z, acc[i][7]+b1v.w);
        *(float4*)(orow + tn*4) = o0;
        *(float4*)(orow + 64 + tn*4) = o1;
    }
}

// ------------- GRU scan: 8 batch-groups x 32 j-slice wgs (grid 256, block 512) -------------
// R6 base, block 256 -> 512: the 8 batches split across two half-blocks (bh2 = tid>>8),
// giving 8 waves/wg = 2 waves/SIMD so LDS/shfl latency is hidden. All sync/exchange
// protocol identical to passing R6.
__global__ __launch_bounds__(512, 1) void gru_scan(const float* __restrict__ xi,
                                                   const float* __restrict__ Wt,
                                                   const float* __restrict__ bhn,
                                                   float* __restrict__ hbuf,
                                                   unsigned int* __restrict__ cnt,
                                                   float* __restrict__ out,
                                                   int chunk_start, int SC) {
    extern __shared__ float smf[];
    float* Wl  = smf;                    // [48][516]
    float* hl  = Wl  + 48*516;           // [8][516]
    float* xil = hl  + 8*516;            // [8][52]
    float* hhl = xil + 8*52;             // [8][49]

    const int tid = threadIdx.x;
    const int grp = blockIdx.x & 7;      // batch group
    const int mem = blockIdx.x >> 3;     // j-slice 0..31
    const int j0 = mem * 16;
    const int b0 = grp * 8;

    // Load Wh slice: 48 gate-cols (c = gate*16+jj) x 512 k, coalesced from Wt[g][k].
    for (int i = tid; i < 48 * 128; i += 512) {
        int c = i >> 7, kq2 = (i & 127) << 2;
        int g = (c >> 4) * HH + j0 + (c & 15);
        *(float4*)&Wl[c * 516 + kq2] = *(const float4*)(Wt + (size_t)g * HH + kq2);
    }
    float bhn_r = 0.f;
    if (tid < 128) bhn_r = bhn[j0 + (tid & 15)];

    const int bh2 = tid >> 8;                 // half-block: batches bh2*4 .. bh2*4+3
    const int tg = (tid & 255) >> 4;          // 16 col-groups
    const int ks = tid & 15;                  // 16 k-slices
    unsigned int* cptr = &cnt[grp << 6];
    unsigned int target = 0;

    for (int s = 0; s < SC; ++s) {
        const int t = chunk_start + s;
        const float* hsrc = hbuf + (size_t)(t & 1) * (BB * HH);
        float*       hdst = hbuf + (size_t)((t + 1) & 1) * (BB * HH);

        // stage h(t) for our 8 batches: 2 x dwordx4 sc0 sc1 per thread (1024 f32x4 total)
        {
            const int lin = tid;                          // 0..511
            const int b_  = lin >> 7;                     // 0..3
            const int kq  = (lin & 127) << 2;
            const float* p0 = hsrc + (size_t)(b0 + b_) * HH + kq;
            const float* p1 = p0 + 4 * HH;                // batches 4..7
            f32x4 h0v, h1v;
            asm volatile(
                "global_load_dwordx4 %0, %2, off sc0 sc1\n\t"
                "global_load_dwordx4 %1, %3, off sc0 sc1\n\t"
                "s_waitcnt vmcnt(0)"
                : "=&v"(h0v), "=&v"(h1v)
                : "v"(p0), "v"(p1)
                : "memory");
            *(f32x4*)&hl[(b_ + 0) * 516 + kq] = h0v;
            *(f32x4*)&hl[(b_ + 4) * 516 + kq] = h1v;
        }
        // stage xi(t) for (8 b x 3 gates x 16 j): 96 float4 (normal cached loads)
        if (tid < 96) {
            int b = tid / 12, q = tid % 12;
            int gate = q >> 2, f = (q & 3) << 2;
            *(float4*)&xil[b * 52 + gate * 16 + f] =
                *(const float4*)(xi + ((size_t)(b0 + b) * SC + s) * G3 + gate * HH + j0 + f);
        }
        __syncthreads();
        // MAC: thread = (bh2, tg, ks): 4 batches x 3 g-cols x 32 k, weights from LDS
        float acc[3][4];
#pragma unroll
        for (int gi = 0; gi < 3; ++gi)
#pragma unroll
            for (int b = 0; b < 4; ++b) acc[gi][b] = 0.f;
#pragma unroll
        for (int m = 0; m < 8; ++m) {
            int k = (ks << 2) + (m << 6);
            float4 w0 = *(const float4*)&Wl[(3*tg+0)*516 + k];
            float4 w1 = *(const float4*)&Wl[(3*tg+1)*516 + k];
            float4 w2 = *(const float4*)&Wl[(3*tg+2)*516 + k];
#pragma unroll
            for (int b = 0; b < 4; ++b) {
                float4 hv = *(const float4*)&hl[(bh2 * 4 + b)*516 + k];
                acc[0][b] += w0.x*hv.x + w0.y*hv.y + w0.z*hv.z + w0.w*hv.w;
                acc[1][b] += w1.x*hv.x + w1.y*hv.y + w1.z*hv.z + w1.w*hv.w;
                acc[2][b] += w2.x*hv.x + w2.y*hv.y + w2.z*hv.z + w2.w*hv.w;
            }
        }
        // reduce over the 16 ks lanes (aligned 16-lane segments) via shfl_xor
#pragma unroll
        for (int gi = 0; gi < 3; ++gi)
#pragma unroll
            for (int b = 0; b < 4; ++b) {
                float v = acc[gi][b];
                v += __shfl_xor(v, 1, 16);
                v += __shfl_xor(v, 2, 16);
                v += __shfl_xor(v, 4, 16);
                v += __shfl_xor(v, 8, 16);
                if (ks == ((gi << 2) | b)) hhl[(bh2 * 4 + b) * 49 + 3 * tg + gi] = v;
            }
        __syncthreads();   // hhl ready
        // gates + state update for (8 b x 16 j)
        if (tid < 128) {
            int b = tid >> 4, jj = tid & 15;
            float hhR = hhl[b*49 + jj];
            float hhZ = hhl[b*49 + 16 + jj];
            float hhN = hhl[b*49 + 32 + jj];
            float xiR = xil[b*52 + jj];
            float xiZ = xil[b*52 + 16 + jj];
            float xiN = xil[b*52 + 32 + jj];
            float hold = hl[b*516 + j0 + jj];
            float r = 1.f / (1.f + expf(-(xiR + hhR)));
            float z = 1.f / (1.f + expf(-(xiZ + hhZ)));
            float n = tanhf(xiN + r * (hhN + bhn_r));
            float hnew = (1.f - z) * n + z * hold;
            float* hp = hdst + (size_t)(b0 + b) * HH + j0 + jj;
            asm volatile("global_store_dword %0, %1, off sc0 sc1"
                         :: "v"(hp), "v"(hnew) : "memory");
            out[((size_t)(b0 + b) * SS + t) * HH + j0 + jj] = hnew;
        }
        // release: sc1 store retirement == visible at coherence point
        asm volatile("s_waitcnt vmcnt(0)" ::: "memory");
        __syncthreads();
        target += 32;
        if (tid == 0) {
            __hip_atomic_fetch_add(cptr, 1u, __ATOMIC_RELAXED, __HIP_MEMORY_SCOPE_AGENT);
            unsigned int v;
            do {
                asm volatile(
                    "global_load_dword %0, %1, off sc0 sc1\n\t"
                    "s_waitcnt vmcnt(0)"
                    : "=v"(v) : "v"(cptr) : "memory");
                if (v >= target) break;
                asm volatile("s_sleep 1");
            } while (true);
        }
        __syncthreads();
    }
}

extern "C" void kernel_launch(void* const* d_in, const int* in_sizes, int n_in,
                              void* d_out, int out_size, void* d_ws, size_t ws_size,
                              hipStream_t stream) {
    const int*   tokens = (const int*)d_in[0];
    const float* emb    = (const float*)d_in[1];
    const float* Wi     = (const float*)d_in[2];
    const float* bi     = (const float*)d_in[3];
    const float* Wh     = (const float*)d_in[4];
    const float* bhn    = (const float*)d_in[5];
    float* out = (float*)d_out;

    char* ws = (char*)d_ws;
    float*        Wt   = (float*)ws;                                  // 3 MB
    float*        hbuf = (float*)(ws + (3 << 20));                    // 2 x 128 KB ping-pong
    unsigned int* cnt  = (unsigned int*)(ws + (3 << 20) + BB*HH*2*4); // 8 x 256B counters
    float*        xi   = (float*)(ws + (4 << 20));                    // chunk xi buffer

    size_t avail = ws_size > ((size_t)4 << 20) ? ws_size - ((size_t)4 << 20) : 0;
    int SC = 64;
    const int cands[5] = {2048, 1024, 512, 256, 128};
    for (int i = 0; i < 5; ++i) {
        if ((size_t)cands[i] * BB * G3 * 4 <= avail) { SC = cands[i]; break; }
    }

    hipFuncSetAttribute((const void*)gru_scan,
                        hipFuncAttributeMaxDynamicSharedMemorySize, SMEM_BYTES);

    hipMemsetAsync(hbuf, 0, BB * HH * 2 * 4, stream);
    transpose_wh<<<768, 256, 0, stream>>>(Wh, Wt);

    int nch = SS / SC;
    for (int c = 0; c < nch; ++c) {
        int cs = c * SC;
        xi_gemm<<<dim3((BB * SC) / 128, 12), 256, 0, stream>>>(tokens, emb, Wi, bi, xi, cs, SC);
        hipMemsetAsync(cnt, 0, 8 * 64 * 4, stream);
        void* args[] = {(void*)&xi, (void*)&Wt, (void*)&bhn, (void*)&hbuf,
                        (void*)&cnt, (void*)&out, (void*)&cs, (void*)&SC};
        hipError_t ce = hipLaunchCooperativeKernel((void*)gru_scan, dim3(256), dim3(512),
                                                   args, SMEM_BYTES, stream);
        if (ce != hipSuccess) {
            // Fallback: plain launch. 256 blocks at 1 block/CU on 256 CUs -> co-resident.
            gru_scan<<<dim3(256), dim3(512), SMEM_BYTES, stream>>>(
                xi, Wt, bhn, hbuf, cnt, out, cs, SC);
        }
    }
}

// Round 10
// 15347.243 us; speedup vs baseline: 1.4502x; 1.1080x over previous
//
#include <hip/hip_runtime.h>
#include <cstdint>
#include <cstddef>

#define HH 512
#define DD 256
#define BB 64
#define SS 2048
#define G3 1536

typedef float f32x4 __attribute__((ext_vector_type(4)));

// LDS layout for gru_scan (floats): Wl[48][516] | hl[8][516] | xil[8][52] | hhl[8][49]
#define SMEM_FLOATS (48*516 + 8*516 + 8*52 + 8*49)
#define SMEM_BYTES  (SMEM_FLOATS * 4)

// ---------------- Wh [512][1536] -> Wt [1536][512] ----------------
__global__ __launch_bounds__(256) void transpose_wh(const float* __restrict__ Wh,
                                                    float* __restrict__ Wt) {
    __shared__ float t[32][33];
    int bx = blockIdx.x % 48;            // g tile
    int by = blockIdx.x / 48;            // k tile
    int x = threadIdx.x & 31, y0 = threadIdx.x >> 5;
#pragma unroll
    for (int i = 0; i < 32; i += 8)
        t[y0 + i][x] = Wh[(size_t)(by * 32 + y0 + i) * G3 + bx * 32 + x];
    __syncthreads();
#pragma unroll
    for (int i = 0; i < 32; i += 8)
        Wt[(size_t)(bx * 32 + y0 + i) * HH + by * 32 + x] = t[x][y0 + i];
}

// ------------- fused embedding gather + xi GEMM: xi[m][g] = emb[tok(m)] @ Wi + bi -------------
__global__ __launch_bounds__(256, 2) void xi_gemm(const int* __restrict__ tokens,
                                                  const float* __restrict__ emb,
                                                  const float* __restrict__ Wi,
                                                  const float* __restrict__ bi,
                                                  float* __restrict__ xi,
                                                  int chunk_start, int SC) {
    __shared__ float Al[8][132];
    __shared__ float Bl[8][132];
    __shared__ int   toks[128];
    const int tid = threadIdx.x;
    const int m0 = blockIdx.x * 128;
    const int n0 = blockIdx.y * 128;
    if (tid < 128) {
        int m = m0 + tid;
        int b = m / SC, s = m % SC;
        toks[tid] = tokens[b * SS + chunk_start + s];
    }
    float acc[8][8];
#pragma unroll
    for (int i = 0; i < 8; ++i)
#pragma unroll
        for (int j = 0; j < 8; ++j) acc[i][j] = 0.f;
    const int tm = tid & 15, tn = (tid >> 4) & 15;
    const int ma = tid & 127, kq = tid >> 7;
    const int bk = tid >> 5,  bn = tid & 31;
    __syncthreads();
    for (int k0 = 0; k0 < DD; k0 += 8) {
        float4 av = *(const float4*)(emb + (size_t)toks[ma] * DD + k0 + kq * 4);
        float4 bv = *(const float4*)(Wi + (size_t)(k0 + bk) * G3 + n0 + bn * 4);
        Al[kq*4+0][ma] = av.x; Al[kq*4+1][ma] = av.y;
        Al[kq*4+2][ma] = av.z; Al[kq*4+3][ma] = av.w;
        *(float4*)&Bl[bk][bn*4] = bv;
        __syncthreads();
#pragma unroll
        for (int k = 0; k < 8; ++k) {
            float a[8], bbv[8];
            *(float4*)&a[0]   = *(const float4*)&Al[k][tm*4];
            *(float4*)&a[4]   = *(const float4*)&Al[k][64 + tm*4];
            *(float4*)&bbv[0] = *(const float4*)&Bl[k][tn*4];
            *(float4*)&bbv[4] = *(const float4*)&Bl[k][64 + tn*4];
#pragma unroll
            for (int i = 0; i < 8; ++i)
#pragma unroll
                for (int j = 0; j < 8; ++j) acc[i][j] += a[i] * bbv[j];
        }
        __syncthreads();
    }
    float4 b0v = *(const float4*)(bi + n0 + tn*4);
    float4 b1v = *(const float4*)(bi + n0 + 64 + tn*4);
#pragma unroll
    for (int i = 0; i < 8; ++i) {
        int m = m0 + (i < 4 ? tm*4 + i : 64 + tm*4 + (i - 4));
        float* orow = xi + (size_t)m * G3 + n0;
        float4 o0 = make_float4(acc[i][0]+b0v.x, acc[i][1]+b0v.y, acc[i][2]+b0v.z, acc[i][3]+b0v.w);
        float4 o1 = make_float4(acc[i][4]+b1v.x, acc[i][5]+b1v.y, acc[i][6]+b1v.z, acc[i][7]+b1v.w);
        *(float4*)(orow + tn*4) = o0;
        *(float4*)(orow + 64 + tn*4) = o1;
    }
}

// ------------- GRU scan: 8 batch-groups x 32 j-slice wgs (grid 256, block 512) -------------
// R7 compute verbatim; ALL cross-wg traffic sc0 sc1 (L3 coherence point, proven R2/R6/R7).
// Epilogue restructured: h-store-only drain -> flag post -> out store + xi(s+1) prefetch
// issued under the barrier wait -> poll on wave 7 (no outstanding VMEM). Flag-word barrier
// (parallel arrival) replaces the 32-serialized-RMW atomic counter.
__global__ __launch_bounds__(512, 1) void gru_scan(const float* __restrict__ xi,
                                                   const float* __restrict__ Wt,
                                                   const float* __restrict__ bhn,
                                                   float* __restrict__ hbuf,
                                                   unsigned int* __restrict__ sync,
                                                   float* __restrict__ out,
                                                   int chunk_start, int SC) {
    extern __shared__ float smf[];
    float* Wl  = smf;                    // [48][516]
    float* hl  = Wl  + 48*516;           // [8][516]
    float* xil = hl  + 8*516;            // [8][52]
    float* hhl = xil + 8*52;             // [8][49]

    const int tid = threadIdx.x;
    const int grp = blockIdx.x & 7;      // batch group (identity, as R7)
    const int mem = blockIdx.x >> 3;     // j-slice 0..31
    const int j0 = mem * 16;
    const int b0 = grp * 8;

    unsigned int* flags = sync + 1024;   // 8*32 flag words, 64B apart (16 KB)
    unsigned int* myflag = flags + (((grp << 5) | mem) << 4);
    const unsigned int* pollbase = flags + ((grp << 5) << 4);

    // Load Wh slice: 48 gate-cols (c = gate*16+jj) x 512 k, coalesced from Wt[g][k].
    for (int i = tid; i < 48 * 128; i += 512) {
        int c = i >> 7, kq2 = (i & 127) << 2;
        int g = (c >> 4) * HH + j0 + (c & 15);
        *(float4*)&Wl[c * 516 + kq2] = *(const float4*)(Wt + (size_t)g * HH + kq2);
    }
    float bhn_r = 0.f;
    if (tid < 128) bhn_r = bhn[j0 + (tid & 15)];

    const int bh2 = tid >> 8;                 // half-block: batches bh2*4 .. bh2*4+3
    const int tg = (tid & 255) >> 4;          // 16 col-groups
    const int ks = tid & 15;                  // 16 k-slices

    // xi prefetch lane mapping (constant per thread); prologue: load xi(step 0)
    const int xb = tid / 12, xq = tid - xb * 12;
    const int xgate = xq >> 2, xf = (xq & 3) << 2;
    const int xoff = xb * 52 + xgate * 16 + xf;
    f32x4 xv = {0.f, 0.f, 0.f, 0.f};
    if (tid < 96)
        xv = *(const f32x4*)(xi + ((size_t)(b0 + xb) * SC) * G3 + xgate * HH + j0 + xf);

    for (int s = 0; s < SC; ++s) {
        const int t = chunk_start + s;
        const float* hsrc = hbuf + (size_t)(t & 1) * (BB * HH);
        float*       hdst = hbuf + (size_t)((t + 1) & 1) * (BB * HH);

        // write prefetched xi(s) to LDS (loaded during previous step's barrier wait)
        if (tid < 96) *(f32x4*)&xil[xoff] = xv;

        // stage h(t) for our 8 batches: 2 x dwordx4 sc0 sc1 per thread
        {
            const int b_  = tid >> 7;                     // 0..3
            const int kq  = (tid & 127) << 2;
            const float* p0 = hsrc + (size_t)(b0 + b_) * HH + kq;
            const float* p1 = p0 + 4 * HH;                // batches 4..7
            f32x4 h0v, h1v;
            asm volatile(
                "global_load_dwordx4 %0, %2, off sc0 sc1\n\t"
                "global_load_dwordx4 %1, %3, off sc0 sc1\n\t"
                "s_waitcnt vmcnt(0)"
                : "=&v"(h0v), "=&v"(h1v) : "v"(p0), "v"(p1) : "memory");
            *(f32x4*)&hl[(b_ + 0) * 516 + kq] = h0v;
            *(f32x4*)&hl[(b_ + 4) * 516 + kq] = h1v;
        }
        __syncthreads();
        // MAC: thread = (bh2, tg, ks): 4 batches x 3 g-cols x 32 k, weights from LDS
        float acc[3][4];
#pragma unroll
        for (int gi = 0; gi < 3; ++gi)
#pragma unroll
            for (int b = 0; b < 4; ++b) acc[gi][b] = 0.f;
#pragma unroll
        for (int m = 0; m < 8; ++m) {
            int k = (ks << 2) + (m << 6);
            float4 w0 = *(const float4*)&Wl[(3*tg+0)*516 + k];
            float4 w1 = *(const float4*)&Wl[(3*tg+1)*516 + k];
            float4 w2 = *(const float4*)&Wl[(3*tg+2)*516 + k];
#pragma unroll
            for (int b = 0; b < 4; ++b) {
                float4 hv = *(const float4*)&hl[(bh2 * 4 + b)*516 + k];
                acc[0][b] += w0.x*hv.x + w0.y*hv.y + w0.z*hv.z + w0.w*hv.w;
                acc[1][b] += w1.x*hv.x + w1.y*hv.y + w1.z*hv.z + w1.w*hv.w;
                acc[2][b] += w2.x*hv.x + w2.y*hv.y + w2.z*hv.z + w2.w*hv.w;
            }
        }
        // reduce over the 16 ks lanes (aligned 16-lane segments) via shfl_xor
#pragma unroll
        for (int gi = 0; gi < 3; ++gi)
#pragma unroll
            for (int b = 0; b < 4; ++b) {
                float v = acc[gi][b];
                v += __shfl_xor(v, 1, 16);
                v += __shfl_xor(v, 2, 16);
                v += __shfl_xor(v, 4, 16);
                v += __shfl_xor(v, 8, 16);
                if (ks == ((gi << 2) | b)) hhl[(bh2 * 4 + b) * 49 + 3 * tg + gi] = v;
            }
        __syncthreads();   // hhl ready
        // gates + state update for (8 b x 16 j): store h ONLY (out deferred past the post)
        float hnew = 0.f;
        float* op = nullptr;
        if (tid < 128) {
            int b = tid >> 4, jj = tid & 15;
            float hhR = hhl[b*49 + jj];
            float hhZ = hhl[b*49 + 16 + jj];
            float hhN = hhl[b*49 + 32 + jj];
            float xiR = xil[b*52 + jj];
            float xiZ = xil[b*52 + 16 + jj];
            float xiN = xil[b*52 + 32 + jj];
            float hold = hl[b*516 + j0 + jj];
            float r = 1.f / (1.f + expf(-(xiR + hhR)));
            float z = 1.f / (1.f + expf(-(xiZ + hhZ)));
            float n = tanhf(xiN + r * (hhN + bhn_r));
            hnew = (1.f - z) * n + z * hold;
            float* hp = hdst + (size_t)(b0 + b) * HH + j0 + jj;
            asm volatile("global_store_dword %0, %1, off sc0 sc1"
                         :: "v"(hp), "v"(hnew) : "memory");
            op = out + ((size_t)(b0 + b) * SS + t) * HH + j0 + jj;
        }
        // release: drain h stores to L3 (out stores not yet issued -> not in the drain)
        asm volatile("s_waitcnt vmcnt(0)" ::: "memory");
        __syncthreads();                       // whole wg's h slices at coherence point
        const unsigned int sv = (unsigned int)(s + 1);
        if (tid == 0)                          // post arrival FIRST
            asm volatile("global_store_dword %0, %1, off sc0 sc1"
                         :: "v"(myflag), "v"(sv) : "memory");
        if (tid < 128) *op = hnew;             // out store hides under the barrier wait
        if (tid < 96 && s + 1 < SC)            // xi(s+1) prefetch hides under the wait
            xv = *(const f32x4*)(xi + ((size_t)(b0 + xb) * SC + (s + 1)) * G3
                                 + xgate * HH + j0 + xf);
        if (tid >= 448) {                      // poll on wave 7: no outstanding VMEM
            const unsigned int* fp = pollbase + ((tid & 31) << 4);
            while (true) {
                unsigned int v;
                asm volatile("global_load_dword %0, %1, off sc0 sc1\n\ts_waitcnt vmcnt(0)"
                             : "=v"(v) : "v"(fp) : "memory");
                if (__all(v >= sv)) break;
                asm volatile("s_sleep 1");
            }
        }
        __syncthreads();
    }
}

extern "C" void kernel_launch(void* const* d_in, const int* in_sizes, int n_in,
                              void* d_out, int out_size, void* d_ws, size_t ws_size,
                              hipStream_t stream) {
    const int*   tokens = (const int*)d_in[0];
    const float* emb    = (const float*)d_in[1];
    const float* Wi     = (const float*)d_in[2];
    const float* bi     = (const float*)d_in[3];
    const float* Wh     = (const float*)d_in[4];
    const float* bhn    = (const float*)d_in[5];
    float* out = (float*)d_out;

    char* ws = (char*)d_ws;
    float*        Wt   = (float*)ws;                                   // 3 MB
    float*        hbuf = (float*)(ws + (3 << 20));                     // 2 x 128 KB ping-pong
    unsigned int* sync = (unsigned int*)(ws + (3 << 20) + BB*HH*2*4);  // flags at +4KB (20.5 KB total)
    float*        xi   = (float*)(ws + (4 << 20));                     // chunk xi buffer

    size_t avail = ws_size > ((size_t)4 << 20) ? ws_size - ((size_t)4 << 20) : 0;
    int SC = 64;
    const int cands[5] = {2048, 1024, 512, 256, 128};
    for (int i = 0; i < 5; ++i) {
        if ((size_t)cands[i] * BB * G3 * 4 <= avail) { SC = cands[i]; break; }
    }

    hipFuncSetAttribute((const void*)gru_scan,
                        hipFuncAttributeMaxDynamicSharedMemorySize, SMEM_BYTES);

    hipMemsetAsync(hbuf, 0, BB * HH * 2 * 4, stream);
    transpose_wh<<<768, 256, 0, stream>>>(Wh, Wt);

    int nch = SS / SC;
    for (int c = 0; c < nch; ++c) {
        int cs = c * SC;
        xi_gemm<<<dim3((BB * SC) / 128, 12), 256, 0, stream>>>(tokens, emb, Wi, bi, xi, cs, SC);
        hipMemsetAsync(sync, 0, 20480, stream);   // flag words zeroed per chunk
        void* args[] = {(void*)&xi, (void*)&Wt, (void*)&bhn, (void*)&hbuf,
                        (void*)&sync, (void*)&out, (void*)&cs, (void*)&SC};
        hipError_t ce = hipLaunchCooperativeKernel((void*)gru_scan, dim3(256), dim3(512),
                                                   args, SMEM_BYTES, stream);
        if (ce != hipSuccess) {
            // Fallback: plain launch. 256 blocks at 1 block/CU on 256 CUs -> co-resident,
            // so the flag barrier cannot deadlock.
            gru_scan<<<dim3(256), dim3(512), SMEM_BYTES, stream>>>(
                xi, Wt, bhn, hbuf, sync, out, cs, SC);
        }
    }
}

// Round 11
// 11997.250 us; speedup vs baseline: 1.8552x; 1.2792x over previous
//
#include <hip/hip_runtime.h>
#include <cstdint>
#include <cstddef>

#define HH 512
#define DD 256
#define BB 64
#define SS 2048
#define G3 1536

typedef float f32x4 __attribute__((ext_vector_type(4)));

// LDS for gru_scan (floats): hl[8][516] | xil[8][52] | hhl[8][49]  (~19.3 KB used)
// Allocation padded to 84 KB so two blocks can never co-reside on a 160 KB CU ->
// 1 wg/CU co-residency holds even on the plain-launch fallback path.
#define SMEM_BYTES  (84 * 1024)

// ---------------- Wh [512][1536] -> Wt [1536][512] ----------------
__global__ __launch_bounds__(256) void transpose_wh(const float* __restrict__ Wh,
                                                    float* __restrict__ Wt) {
    __shared__ float t[32][33];
    int bx = blockIdx.x % 48;            // g tile
    int by = blockIdx.x / 48;            // k tile
    int x = threadIdx.x & 31, y0 = threadIdx.x >> 5;
#pragma unroll
    for (int i = 0; i < 32; i += 8)
        t[y0 + i][x] = Wh[(size_t)(by * 32 + y0 + i) * G3 + bx * 32 + x];
    __syncthreads();
#pragma unroll
    for (int i = 0; i < 32; i += 8)
        Wt[(size_t)(bx * 32 + y0 + i) * HH + by * 32 + x] = t[x][y0 + i];
}

// ------------- fused embedding gather + xi GEMM: xi[m][g] = emb[tok(m)] @ Wi + bi -------------
__global__ __launch_bounds__(256, 2) void xi_gemm(const int* __restrict__ tokens,
                                                  const float* __restrict__ emb,
                                                  const float* __restrict__ Wi,
                                                  const float* __restrict__ bi,
                                                  float* __restrict__ xi,
                                                  int chunk_start, int SC) {
    __shared__ float Al[8][132];
    __shared__ float Bl[8][132];
    __shared__ int   toks[128];
    const int tid = threadIdx.x;
    const int m0 = blockIdx.x * 128;
    const int n0 = blockIdx.y * 128;
    if (tid < 128) {
        int m = m0 + tid;
        int b = m / SC, s = m % SC;
        toks[tid] = tokens[b * SS + chunk_start + s];
    }
    float acc[8][8];
#pragma unroll
    for (int i = 0; i < 8; ++i)
#pragma unroll
        for (int j = 0; j < 8; ++j) acc[i][j] = 0.f;
    const int tm = tid & 15, tn = (tid >> 4) & 15;
    const int ma = tid & 127, kq = tid >> 7;
    const int bk = tid >> 5,  bn = tid & 31;
    __syncthreads();
    for (int k0 = 0; k0 < DD; k0 += 8) {
        float4 av = *(const float4*)(emb + (size_t)toks[ma] * DD + k0 + kq * 4);
        float4 bv = *(const float4*)(Wi + (size_t)(k0 + bk) * G3 + n0 + bn * 4);
        Al[kq*4+0][ma] = av.x; Al[kq*4+1][ma] = av.y;
        Al[kq*4+2][ma] = av.z; Al[kq*4+3][ma] = av.w;
        *(float4*)&Bl[bk][bn*4] = bv;
        __syncthreads();
#pragma unroll
        for (int k = 0; k < 8; ++k) {
            float a[8], bbv[8];
            *(float4*)&a[0]   = *(const float4*)&Al[k][tm*4];
            *(float4*)&a[4]   = *(const float4*)&Al[k][64 + tm*4];
            *(float4*)&bbv[0] = *(const float4*)&Bl[k][tn*4];
            *(float4*)&bbv[4] = *(const float4*)&Bl[k][64 + tn*4];
#pragma unroll
            for (int i = 0; i < 8; ++i)
#pragma unroll
                for (int j = 0; j < 8; ++j) acc[i][j] += a[i] * bbv[j];
        }
        __syncthreads();
    }
    float4 b0v = *(const float4*)(bi + n0 + tn*4);
    float4 b1v = *(const float4*)(bi + n0 + 64 + tn*4);
#pragma unroll
    for (int i = 0; i < 8; ++i) {
        int m = m0 + (i < 4 ? tm*4 + i : 64 + tm*4 + (i - 4));
        float* orow = xi + (size_t)m * G3 + n0;
        float4 o0 = make_float4(acc[i][0]+b0v.x, acc[i][1]+b0v.y, acc[i][2]+b0v.z, acc[i][3]+b0v.w);
        float4 o1 = make_float4(acc[i][4]+b1v.x, acc[i][5]+b1v.y, acc[i][6]+b1v.z, acc[i][7]+b1v.w);
        *(float4*)(orow + tn*4) = o0;
        *(float4*)(orow + 64 + tn*4) = o1;
    }
}

// ------------- GRU scan: 8 batch-groups x 32 j-slice wgs (grid 256, block 512) -------------
// R10 base + weights in REGISTERS: thread (tg,ks) holds w[3][8] f32x4 (its 3 gate-cols x
// 32 k) for the whole scan -> MAC reads only h from LDS (32 b128/thread/step, was 56).
// Gates use __expf forms. Launch protected: coop-launch error -> plain launch (84 KB LDS
// forces 1 wg/CU so co-residency holds either way). All cross-wg traffic sc0 sc1 (L3).
__global__ __launch_bounds__(512, 1) void gru_scan(const float* __restrict__ xi,
                                                   const float* __restrict__ Wt,
                                                   const float* __restrict__ bhn,
                                                   float* __restrict__ hbuf,
                                                   unsigned int* __restrict__ sync,
                                                   float* __restrict__ out,
                                                   int chunk_start, int SC) {
    extern __shared__ float smf[];
    float* hl  = smf;                    // [8][516]
    float* xil = hl  + 8*516;            // [8][52]
    float* hhl = xil + 8*52;             // [8][49]

    const int tid = threadIdx.x;
    const int grp = blockIdx.x & 7;      // batch group
    const int mem = blockIdx.x >> 3;     // j-slice 0..31
    const int j0 = mem * 16;
    const int b0 = grp * 8;

    unsigned int* flags = sync + 1024;   // 8*32 flag words, 64B apart (16 KB)
    unsigned int* myflag = flags + (((grp << 5) | mem) << 4);
    const unsigned int* pollbase = flags + ((grp << 5) << 4);

    const int bh2 = tid >> 8;                 // half-block: batches bh2*4 .. bh2*4+3
    const int tg = (tid & 255) >> 4;          // 16 col-groups
    const int ks = tid & 15;                  // 16 k-slices

    // persistent weight registers: w[gi][m] = Wt[col(3*tg+gi)][ks*4 + m*64 ..+3]
    // (both half-blocks hold the same (tg,ks) slice -- duplication is free in regs)
    f32x4 w[3][8];
#pragma unroll
    for (int gi = 0; gi < 3; ++gi) {
        const int c = 3 * tg + gi;            // gate = c>>4, jj = c&15
        const float* wp = Wt + (size_t)((c >> 4) * HH + j0 + (c & 15)) * HH + (ks << 2);
#pragma unroll
        for (int m = 0; m < 8; ++m)
            w[gi][m] = *(const f32x4*)(wp + (m << 6));
    }
    float bhn_r = 0.f;
    if (tid < 128) bhn_r = bhn[j0 + (tid & 15)];

    // xi prefetch lane mapping (constant per thread); prologue: load xi(step 0)
    const int xb = tid / 12, xq = tid - xb * 12;
    const int xgate = xq >> 2, xf = (xq & 3) << 2;
    const int xoff = xb * 52 + xgate * 16 + xf;
    f32x4 xv = {0.f, 0.f, 0.f, 0.f};
    if (tid < 96)
        xv = *(const f32x4*)(xi + ((size_t)(b0 + xb) * SC) * G3 + xgate * HH + j0 + xf);

    for (int s = 0; s < SC; ++s) {
        const int t = chunk_start + s;
        const float* hsrc = hbuf + (size_t)(t & 1) * (BB * HH);
        float*       hdst = hbuf + (size_t)((t + 1) & 1) * (BB * HH);

        // write prefetched xi(s) to LDS (loaded during previous step's barrier wait)
        if (tid < 96) *(f32x4*)&xil[xoff] = xv;

        // stage h(t) for our 8 batches: 2 x dwordx4 sc0 sc1 per thread
        {
            const int b_  = tid >> 7;                     // 0..3
            const int kq  = (tid & 127) << 2;
            const float* p0 = hsrc + (size_t)(b0 + b_) * HH + kq;
            const float* p1 = p0 + 4 * HH;                // batches 4..7
            f32x4 h0v, h1v;
            asm volatile(
                "global_load_dwordx4 %0, %2, off sc0 sc1\n\t"
                "global_load_dwordx4 %1, %3, off sc0 sc1\n\t"
                "s_waitcnt vmcnt(0)"
                : "=&v"(h0v), "=&v"(h1v) : "v"(p0), "v"(p1) : "memory");
            *(f32x4*)&hl[(b_ + 0) * 516 + kq] = h0v;
            *(f32x4*)&hl[(b_ + 4) * 516 + kq] = h1v;
        }
        __syncthreads();
        // MAC: thread = (bh2, tg, ks): 4 batches x 3 g-cols x 32 k, weights in regs
        float acc[3][4];
#pragma unroll
        for (int gi = 0; gi < 3; ++gi)
#pragma unroll
            for (int b = 0; b < 4; ++b) acc[gi][b] = 0.f;
#pragma unroll
        for (int m = 0; m < 8; ++m) {
            const int k = (ks << 2) + (m << 6);
            f32x4 hv0 = *(const f32x4*)&hl[(bh2 * 4 + 0)*516 + k];
            f32x4 hv1 = *(const f32x4*)&hl[(bh2 * 4 + 1)*516 + k];
            f32x4 hv2 = *(const f32x4*)&hl[(bh2 * 4 + 2)*516 + k];
            f32x4 hv3 = *(const f32x4*)&hl[(bh2 * 4 + 3)*516 + k];
#pragma unroll
            for (int gi = 0; gi < 3; ++gi) {
                const f32x4 wv = w[gi][m];
                acc[gi][0] += wv.x*hv0.x + wv.y*hv0.y + wv.z*hv0.z + wv.w*hv0.w;
                acc[gi][1] += wv.x*hv1.x + wv.y*hv1.y + wv.z*hv1.z + wv.w*hv1.w;
                acc[gi][2] += wv.x*hv2.x + wv.y*hv2.y + wv.z*hv2.z + wv.w*hv2.w;
                acc[gi][3] += wv.x*hv3.x + wv.y*hv3.y + wv.z*hv3.z + wv.w*hv3.w;
            }
        }
        // reduce over the 16 ks lanes (aligned 16-lane segments) via shfl_xor
#pragma unroll
        for (int gi = 0; gi < 3; ++gi)
#pragma unroll
            for (int b = 0; b < 4; ++b) {
                float v = acc[gi][b];
                v += __shfl_xor(v, 1, 16);
                v += __shfl_xor(v, 2, 16);
                v += __shfl_xor(v, 4, 16);
                v += __shfl_xor(v, 8, 16);
                if (ks == ((gi << 2) | b)) hhl[(bh2 * 4 + b) * 49 + 3 * tg + gi] = v;
            }
        __syncthreads();   // hhl ready
        // gates + state update for (8 b x 16 j): store h ONLY (out deferred past the post)
        float hnew = 0.f;
        float* op = nullptr;
        if (tid < 128) {
            int b = tid >> 4, jj = tid & 15;
            float hhR = hhl[b*49 + jj];
            float hhZ = hhl[b*49 + 16 + jj];
            float hhN = hhl[b*49 + 32 + jj];
            float xiR = xil[b*52 + jj];
            float xiZ = xil[b*52 + 16 + jj];
            float xiN = xil[b*52 + 32 + jj];
            float hold = hl[b*516 + j0 + jj];
            float r = 1.f / (1.f + __expf(-(xiR + hhR)));
            float z = 1.f / (1.f + __expf(-(xiZ + hhZ)));
            float a = xiN + r * (hhN + bhn_r);
            float e = __expf(-2.f * fabsf(a));            // overflow-safe tanh
            float n = copysignf((1.f - e) / (1.f + e), a);
            hnew = (1.f - z) * n + z * hold;
            float* hp = hdst + (size_t)(b0 + b) * HH + j0 + jj;
            asm volatile("global_store_dword %0, %1, off sc0 sc1"
                         :: "v"(hp), "v"(hnew) : "memory");
            op = out + ((size_t)(b0 + b) * SS + t) * HH + j0 + jj;
        }
        // release: drain h stores to L3 (out stores not yet issued -> not in the drain)
        asm volatile("s_waitcnt vmcnt(0)" ::: "memory");
        __syncthreads();                       // whole wg's h slices at coherence point
        const unsigned int sv = (unsigned int)(s + 1);
        if (tid == 0)                          // post arrival FIRST
            asm volatile("global_store_dword %0, %1, off sc0 sc1"
                         :: "v"(myflag), "v"(sv) : "memory");
        if (tid < 128) *op = hnew;             // out store hides under the barrier wait
        if (tid < 96 && s + 1 < SC)            // xi(s+1) prefetch hides under the wait
            xv = *(const f32x4*)(xi + ((size_t)(b0 + xb) * SC + (s + 1)) * G3
                                 + xgate * HH + j0 + xf);
        if (tid >= 448) {                      // poll on wave 7: no outstanding VMEM
            const unsigned int* fp = pollbase + ((tid & 31) << 4);
            while (true) {
                unsigned int v;
                asm volatile("global_load_dword %0, %1, off sc0 sc1\n\ts_waitcnt vmcnt(0)"
                             : "=v"(v) : "v"(fp) : "memory");
                if (__all(v >= sv)) break;
                asm volatile("s_sleep 1");
            }
        }
        __syncthreads();
    }
}

extern "C" void kernel_launch(void* const* d_in, const int* in_sizes, int n_in,
                              void* d_out, int out_size, void* d_ws, size_t ws_size,
                              hipStream_t stream) {
    const int*   tokens = (const int*)d_in[0];
    const float* emb    = (const float*)d_in[1];
    const float* Wi     = (const float*)d_in[2];
    const float* bi     = (const float*)d_in[3];
    const float* Wh     = (const float*)d_in[4];
    const float* bhn    = (const float*)d_in[5];
    float* out = (float*)d_out;

    char* ws = (char*)d_ws;
    float*        Wt   = (float*)ws;                                   // 3 MB
    float*        hbuf = (float*)(ws + (3 << 20));                     // 2 x 128 KB ping-pong
    unsigned int* sync = (unsigned int*)(ws + (3 << 20) + BB*HH*2*4);  // flags at +4KB
    float*        xi   = (float*)(ws + (4 << 20));                     // chunk xi buffer

    size_t avail = ws_size > ((size_t)4 << 20) ? ws_size - ((size_t)4 << 20) : 0;
    int SC = 64;
    const int cands[5] = {2048, 1024, 512, 256, 128};
    for (int i = 0; i < 5; ++i) {
        if ((size_t)cands[i] * BB * G3 * 4 <= avail) { SC = cands[i]; break; }
    }

    hipFuncSetAttribute((const void*)gru_scan,
                        hipFuncAttributeMaxDynamicSharedMemorySize, SMEM_BYTES);

    hipMemsetAsync(hbuf, 0, BB * HH * 2 * 4, stream);
    transpose_wh<<<768, 256, 0, stream>>>(Wh, Wt);

    int nch = SS / SC;
    for (int c = 0; c < nch; ++c) {
        int cs = c * SC;
        xi_gemm<<<dim3((BB * SC) / 128, 12), 256, 0, stream>>>(tokens, emb, Wi, bi, xi, cs, SC);
        hipMemsetAsync(sync, 0, 20480, stream);   // flag words zeroed per chunk
        void* args[] = {(void*)&xi, (void*)&Wt, (void*)&bhn, (void*)&hbuf,
                        (void*)&sync, (void*)&out, (void*)&cs, (void*)&SC};
        hipError_t ce = hipLaunchCooperativeKernel((void*)gru_scan, dim3(256), dim3(512),
                                                   args, SMEM_BYTES, stream);
        if (ce != hipSuccess) {
            // Fallback: plain launch. 256 blocks, 84 KB LDS -> exactly 1 wg/CU on 256 CUs
            // -> co-resident, so the flag barrier cannot deadlock.
            gru_scan<<<dim3(256), dim3(512), SMEM_BYTES, stream>>>(
                xi, Wt, bhn, hbuf, sync, out, cs, SC);
        }
    }
}